// Round 1
// baseline (191.617 us; speedup 1.0000x reference)
//
#include <hip/hip_runtime.h>

#define DIM   4096
#define BATCH 2048
#define KNZ   40
#define ROWS  4
#define LROW  4160   // 4096 + 64 pad words; phys(j) = j + (j>>6)
#define DPT   16     // 4096 d's / 256 threads

__device__ __forceinline__ float shflx(float v, int m) { return __shfl_xor(v, m, 64); }
__device__ __forceinline__ float shfls(float v, int s) { return __shfl(v, s, 64); }

// In-lane stage for h <= 32: blocks of 2H live inside each lane's 64-elem chunk.
template<int H>
__device__ __forceinline__ void stage_inlane(float v[64]) {
#pragma unroll
  for (int o = 0; o < 64; o += 2 * H) {
    float dt[H];
#pragma unroll
    for (int i = 0; i < H; ++i) {
      float a = v[o + i], b = v[o + H + i];
      dt[i] = a - b;          // diff = left - right
      v[o + i] = a + b;       // sum branch in place
    }
#pragma unroll
    for (int i = H - 1; i >= 1; --i) v[o + H + i] = dt[i] + dt[i - 1];
    v[o + H] = dt[0] + dt[H - 1];   // i==0 wraps to diff[H-1]
  }
}

// Cross-lane stage for h >= 64. HL = h/64 in {32,16,8,4,2,1}.
// lane l holds row[64l + r]. Pair partner = lane l^HL, same r.
template<int HL>
__device__ __forceinline__ void stage_xlane(float v[64], int lane) {
  const bool up = (lane & HL) != 0;
  // source lane for the r==0 roll neighbor (d[63] of lane-1, or wrap to top of half-block)
  const int srcl = ((lane & (HL - 1)) == 0) ? (lane | (HL - 1)) : (lane - 1);
#pragma unroll
  for (int r = 0; r < 64; ++r) {
    float pv = shflx(v[r], HL);
    float s = v[r] + pv;                     // sum (both lanes)
    float d = up ? (pv - v[r]) : (v[r] - pv); // left - right (both lanes agree)
    v[r] = up ? d : s;                        // lower keeps sum, upper keeps diff
  }
  float dw = shfls(v[63], srcl);              // neighbor's d[63] for the r==0 roll
#pragma unroll
  for (int r = 63; r >= 1; --r) {             // descending: v[r-1] still holds diff
    float d2 = v[r] + v[r - 1];
    v[r] = up ? d2 : v[r];
  }
  float d2 = v[0] + dw;
  v[0] = up ? d2 : v[0];
}

__device__ __forceinline__ void fhh_regs(float v[64], int lane) {
  stage_xlane<32>(v, lane);  // h=2048
  stage_xlane<16>(v, lane);  // h=1024
  stage_xlane<8>(v, lane);   // h=512
  stage_xlane<4>(v, lane);   // h=256
  stage_xlane<2>(v, lane);   // h=128
  stage_xlane<1>(v, lane);   // h=64
  stage_inlane<32>(v);       // h=32
  stage_inlane<16>(v);
  stage_inlane<8>(v);
  stage_inlane<4>(v);
  stage_inlane<2>(v);
  stage_inlane<1>(v);        // h=1
}

__global__ __launch_bounds__(256, 2) void aleph_fused(
    const float* __restrict__ x, const float* __restrict__ sw,
    const float* __restrict__ V, const int* __restrict__ I,
    float* __restrict__ out) {
  __shared__ float lds[ROWS * LROW];
  const int t = threadIdx.x;
  const int w = t >> 6;          // wave id = row within block
  const int lane = t & 63;
  const size_t row = (size_t)blockIdx.x * ROWS + w;

  float v[64];
  {
    const float4* xp = (const float4*)(x + row * DIM + (size_t)lane * 64);
#pragma unroll
    for (int i = 0; i < 16; ++i) {
      float4 f = xp[i];
      v[4 * i] = f.x; v[4 * i + 1] = f.y; v[4 * i + 2] = f.z; v[4 * i + 3] = f.w;
    }
  }
  fhh_regs(v, lane);   // v = wave chunk

  // Fill LDS row (pad-65: phys(64l + r) = 65l + r) — conflict-free b32 writes.
  float* myrow = lds + w * LROW + 65 * lane;
#pragma unroll
  for (int r = 0; r < 64; ++r) myrow[r] = v[r];
  __syncthreads();

  // Gather phase: thread t owns d = ii*256 + t for all 4 rows (shares I/V loads 4-way).
  float preg[DPT][ROWS];
#pragma unroll
  for (int ii = 0; ii < DPT; ++ii) {
    const int d = ii * 256 + t;
    const int pd = d + (d >> 6);
    const float swd = sw[d];
    float a0 = lds[0 * LROW + pd] * swd;
    float a1 = lds[1 * LROW + pd] * swd;
    float a2 = lds[2 * LROW + pd] * swd;
    float a3 = lds[3 * LROW + pd] * swd;
    const int4*   ip = (const int4*)(I + d * KNZ);
    const float4* vp = (const float4*)(V + d * KNZ);
    for (int g = 0; g < KNZ / 4; ++g) {   // runtime loop: no local-array indexing inside
      int4 i4 = ip[g];
      float4 f4 = vp[g];
      int p0 = i4.x + (i4.x >> 6);
      int p1 = i4.y + (i4.y >> 6);
      int p2 = i4.z + (i4.z >> 6);
      int p3 = i4.w + (i4.w >> 6);
      a0 += lds[0 * LROW + p0] * f4.x; a1 += lds[1 * LROW + p0] * f4.x;
      a2 += lds[2 * LROW + p0] * f4.x; a3 += lds[3 * LROW + p0] * f4.x;
      a0 += lds[0 * LROW + p1] * f4.y; a1 += lds[1 * LROW + p1] * f4.y;
      a2 += lds[2 * LROW + p1] * f4.y; a3 += lds[3 * LROW + p1] * f4.y;
      a0 += lds[0 * LROW + p2] * f4.z; a1 += lds[1 * LROW + p2] * f4.z;
      a2 += lds[2 * LROW + p2] * f4.z; a3 += lds[3 * LROW + p2] * f4.z;
      a0 += lds[0 * LROW + p3] * f4.w; a1 += lds[1 * LROW + p3] * f4.w;
      a2 += lds[2 * LROW + p3] * f4.w; a3 += lds[3 * LROW + p3] * f4.w;
    }
    preg[ii][0] = a0; preg[ii][1] = a1; preg[ii][2] = a2; preg[ii][3] = a3;
  }
  __syncthreads();   // all gathers done before overwriting wave in place
#pragma unroll
  for (int ii = 0; ii < DPT; ++ii) {
    const int d = ii * 256 + t;
    const int pd = d + (d >> 6);
    lds[0 * LROW + pd] = preg[ii][0];
    lds[1 * LROW + pd] = preg[ii][1];
    lds[2 * LROW + pd] = preg[ii][2];
    lds[3 * LROW + pd] = preg[ii][3];
  }
  __syncthreads();

  // Reload processed row chunk, second FHH, scale, store.
#pragma unroll
  for (int r = 0; r < 64; ++r) v[r] = myrow[r];
  fhh_regs(v, lane);

  const float inv = 1.0f / (float)DIM;
  float4* op = (float4*)(out + row * DIM + (size_t)lane * 64);
#pragma unroll
  for (int i = 0; i < 16; ++i) {
    float4 f;
    f.x = v[4 * i] * inv;     f.y = v[4 * i + 1] * inv;
    f.z = v[4 * i + 2] * inv; f.w = v[4 * i + 3] * inv;
    op[i] = f;
  }
}

extern "C" void kernel_launch(void* const* d_in, const int* in_sizes, int n_in,
                              void* d_out, int out_size, void* d_ws, size_t ws_size,
                              hipStream_t stream) {
  const float* x  = (const float*)d_in[0];   // (2048, 4096) f32
  const float* sw = (const float*)d_in[1];   // (4096,) f32
  const float* V  = (const float*)d_in[2];   // (4096, 40) f32  engram_values
  const int*   I  = (const int*)d_in[3];     // (4096, 40) i32  engram_indices
  float* out = (float*)d_out;                // (2048, 4096) f32

  dim3 grid(BATCH / ROWS), block(256);
  hipLaunchKernelGGL(aleph_fused, grid, block, 0, stream, x, sw, V, I, out);
}

// Round 2
// 145.281 us; speedup vs baseline: 1.3189x; 1.3189x over previous
//
#include <hip/hip_runtime.h>

#define DIM   4096
#define BATCH 2048
#define KNZ   40
#define ROWS  4
#define DPT   16     // 4096 d's / 256 threads

__device__ __forceinline__ float shflx(float v, int m) { return __shfl_xor(v, m, 64); }
__device__ __forceinline__ float shfls(float v, int s) { return __shfl(v, s, 64); }

// byte offset of (d, row=0) in the interleaved bf16 LDS image.
// XOR-swizzle bits 3..7 with (d>>6)&31 so fixed-r per-lane accesses spread banks.
__device__ __forceinline__ int swz(int d) { return (d << 3) ^ ((d >> 3) & 248); }

// f32 -> bf16 (RNE), bf16 -> f32 helpers (bit ops, no NaN handling needed)
__device__ __forceinline__ unsigned short bfp(float f) {
  unsigned u = __float_as_uint(f);
  u += 0x7fffu + ((u >> 16) & 1u);
  return (unsigned short)(u >> 16);
}
__device__ __forceinline__ float bfu(unsigned short h) {
  return __uint_as_float(((unsigned)h) << 16);
}

// In-lane stage for h <= 32: blocks of 2H live inside each lane's 64-elem chunk.
template<int H>
__device__ __forceinline__ void stage_inlane(float v[64]) {
#pragma unroll
  for (int o = 0; o < 64; o += 2 * H) {
    float dt[H];
#pragma unroll
    for (int i = 0; i < H; ++i) {
      float a = v[o + i], b = v[o + H + i];
      dt[i] = a - b;
      v[o + i] = a + b;
    }
#pragma unroll
    for (int i = H - 1; i >= 1; --i) v[o + H + i] = dt[i] + dt[i - 1];
    v[o + H] = dt[0] + dt[H - 1];
  }
}

// Cross-lane stage for h >= 64. HL = h/64 in {32,16,8,4,2,1}.
template<int HL>
__device__ __forceinline__ void stage_xlane(float v[64], int lane) {
  const bool up = (lane & HL) != 0;
  const int srcl = ((lane & (HL - 1)) == 0) ? (lane | (HL - 1)) : (lane - 1);
#pragma unroll
  for (int r = 0; r < 64; ++r) {
    float pv = shflx(v[r], HL);
    float s = v[r] + pv;
    float d = up ? (pv - v[r]) : (v[r] - pv);
    v[r] = up ? d : s;
  }
  float dw = shfls(v[63], srcl);
#pragma unroll
  for (int r = 63; r >= 1; --r) {
    float d2 = v[r] + v[r - 1];
    v[r] = up ? d2 : v[r];
  }
  float d2 = v[0] + dw;
  v[0] = up ? d2 : v[0];
}

__device__ __forceinline__ void fhh_regs(float v[64], int lane) {
  stage_xlane<32>(v, lane);
  stage_xlane<16>(v, lane);
  stage_xlane<8>(v, lane);
  stage_xlane<4>(v, lane);
  stage_xlane<2>(v, lane);
  stage_xlane<1>(v, lane);
  stage_inlane<32>(v);
  stage_inlane<16>(v);
  stage_inlane<8>(v);
  stage_inlane<4>(v);
  stage_inlane<2>(v);
  stage_inlane<1>(v);
}

__global__ __launch_bounds__(256, 4) void aleph_fused(
    const float* __restrict__ x, const float* __restrict__ sw,
    const float* __restrict__ V, const int* __restrict__ I,
    float* __restrict__ out) {
  // interleaved bf16: (d, row) at byte swz(d) + 2*row.  32 KB total.
  __shared__ unsigned short lds[DIM * ROWS];
  char* lb = (char*)lds;
  const int t = threadIdx.x;
  const int w = t >> 6;
  const int lane = t & 63;
  const size_t row = (size_t)blockIdx.x * ROWS + w;

  float v[64];
  {
    const float4* xp = (const float4*)(x + row * DIM + (size_t)lane * 64);
#pragma unroll
    for (int i = 0; i < 16; ++i) {
      float4 f = xp[i];
      v[4 * i] = f.x; v[4 * i + 1] = f.y; v[4 * i + 2] = f.z; v[4 * i + 3] = f.w;
    }
  }
  fhh_regs(v, lane);   // v = wave chunk (lane holds d = 64*lane + r)

  // Fill: b16 writes, fixed r across lanes -> banks 2*((r^l)&31): 2 lanes/bank (free).
#pragma unroll
  for (int r = 0; r < 64; ++r) {
    int d = 64 * lane + r;
    *(unsigned short*)(lb + swz(d) + 2 * w) = bfp(v[r]);
  }
  __syncthreads();

  // Gather: thread t owns d = ii*256 + t; one ds_read_b64 yields all 4 rows.
  float preg[DPT][ROWS];
#pragma unroll
  for (int ii = 0; ii < DPT; ++ii) {
    const int d = ii * 256 + t;
    const float swd = sw[d];
    uint2 u0 = *(const uint2*)(lb + swz(d));
    float a0 = __uint_as_float(u0.x << 16) * swd;
    float a1 = __uint_as_float(u0.x & 0xffff0000u) * swd;
    float a2 = __uint_as_float(u0.y << 16) * swd;
    float a3 = __uint_as_float(u0.y & 0xffff0000u) * swd;
    const int4*   ip = (const int4*)(I + d * KNZ);
    const float4* vp = (const float4*)(V + d * KNZ);
#pragma unroll 5
    for (int g = 0; g < KNZ / 4; ++g) {
      int4 i4 = ip[g];
      float4 f4 = vp[g];
      uint2 ua = *(const uint2*)(lb + swz(i4.x));
      uint2 ub = *(const uint2*)(lb + swz(i4.y));
      uint2 uc = *(const uint2*)(lb + swz(i4.z));
      uint2 ud = *(const uint2*)(lb + swz(i4.w));
      a0 += __uint_as_float(ua.x << 16) * f4.x;
      a1 += __uint_as_float(ua.x & 0xffff0000u) * f4.x;
      a2 += __uint_as_float(ua.y << 16) * f4.x;
      a3 += __uint_as_float(ua.y & 0xffff0000u) * f4.x;
      a0 += __uint_as_float(ub.x << 16) * f4.y;
      a1 += __uint_as_float(ub.x & 0xffff0000u) * f4.y;
      a2 += __uint_as_float(ub.y << 16) * f4.y;
      a3 += __uint_as_float(ub.y & 0xffff0000u) * f4.y;
      a0 += __uint_as_float(uc.x << 16) * f4.z;
      a1 += __uint_as_float(uc.x & 0xffff0000u) * f4.z;
      a2 += __uint_as_float(uc.y << 16) * f4.z;
      a3 += __uint_as_float(uc.y & 0xffff0000u) * f4.z;
      a0 += __uint_as_float(ud.x << 16) * f4.w;
      a1 += __uint_as_float(ud.x & 0xffff0000u) * f4.w;
      a2 += __uint_as_float(ud.y << 16) * f4.w;
      a3 += __uint_as_float(ud.y & 0xffff0000u) * f4.w;
    }
    preg[ii][0] = a0; preg[ii][1] = a1; preg[ii][2] = a2; preg[ii][3] = a3;
  }
  __syncthreads();   // all gathers done before overwriting wave in place

  // Write processed back: 4 rows packed -> one ds_write_b64 per d.
#pragma unroll
  for (int ii = 0; ii < DPT; ++ii) {
    const int d = ii * 256 + t;
    ushort4 pk;
    pk.x = bfp(preg[ii][0]); pk.y = bfp(preg[ii][1]);
    pk.z = bfp(preg[ii][2]); pk.w = bfp(preg[ii][3]);
    *(ushort4*)(lb + swz(d)) = pk;
  }
  __syncthreads();

  // Reload processed row chunk (b16 reads, conflict-free), second FHH, store.
#pragma unroll
  for (int r = 0; r < 64; ++r) {
    int d = 64 * lane + r;
    v[r] = bfu(*(const unsigned short*)(lb + swz(d) + 2 * w));
  }
  fhh_regs(v, lane);

  const float inv = 1.0f / (float)DIM;
  float4* op = (float4*)(out + row * DIM + (size_t)lane * 64);
#pragma unroll
  for (int i = 0; i < 16; ++i) {
    float4 f;
    f.x = v[4 * i] * inv;     f.y = v[4 * i + 1] * inv;
    f.z = v[4 * i + 2] * inv; f.w = v[4 * i + 3] * inv;
    op[i] = f;
  }
}

extern "C" void kernel_launch(void* const* d_in, const int* in_sizes, int n_in,
                              void* d_out, int out_size, void* d_ws, size_t ws_size,
                              hipStream_t stream) {
  const float* x  = (const float*)d_in[0];   // (2048, 4096) f32
  const float* sw = (const float*)d_in[1];   // (4096,) f32
  const float* V  = (const float*)d_in[2];   // (4096, 40) f32
  const int*   I  = (const int*)d_in[3];     // (4096, 40) i32
  float* out = (float*)d_out;                // (2048, 4096) f32

  dim3 grid(BATCH / ROWS), block(256);
  hipLaunchKernelGGL(aleph_fused, grid, block, 0, stream, x, sw, V, I, out);
}

// Round 4
// 83.953 us; speedup vs baseline: 2.2824x; 1.7305x over previous
//
#include <hip/hip_runtime.h>

#define DIM   4096
#define BATCH 2048
#define KNZ   40
#define ROWS  8
#define TPB   512
#define DPT   (DIM / TPB)   // 8 d's per thread

__device__ __forceinline__ float shflx(float v, int m) { return __shfl_xor(v, m, 64); }
__device__ __forceinline__ float shfls(float v, int s) { return __shfl(v, s, 64); }

// byte offset of the 16B row-group for dim index d (8 bf16 rows interleaved).
// XOR addr bits [8:4] with lane bits l[4:0] (l = d>>6) so lane-chunk access spreads banks.
__device__ __forceinline__ int swz8(int d) { return (d << 4) ^ ((d >> 2) & 0x1f0); }

__device__ __forceinline__ unsigned short bfp(float f) {   // f32 -> bf16 RNE
  unsigned u = __float_as_uint(f);
  u += 0x7fffu + ((u >> 16) & 1u);
  return (unsigned short)(u >> 16);
}
__device__ __forceinline__ float bfu(unsigned short h) { return __uint_as_float(((unsigned)h) << 16); }
__device__ __forceinline__ float blo(unsigned u) { return __uint_as_float(u << 16); }
__device__ __forceinline__ float bhi(unsigned u) { return __uint_as_float(u & 0xffff0000u); }

// In-lane stage for h <= 32: blocks of 2H inside the lane's 64-elem chunk.
template<int H>
__device__ __forceinline__ void stage_inlane(float v[64]) {
#pragma unroll
  for (int o = 0; o < 64; o += 2 * H) {
    float dt[H];
#pragma unroll
    for (int i = 0; i < H; ++i) {
      float a = v[o + i], b = v[o + H + i];
      dt[i] = a - b;
      v[o + i] = a + b;
    }
#pragma unroll
    for (int i = H - 1; i >= 1; --i) v[o + H + i] = dt[i] + dt[i - 1];
    v[o + H] = dt[0] + dt[H - 1];
  }
}

// Cross-lane stage for h >= 64 (HL = h/64): butterfly + roll of diff branch.
// R2-proven pure-shuffle form.
template<int HL>
__device__ __forceinline__ void stage_xlane(float v[64], int lane) {
  const bool up = (lane & HL) != 0;
  const int srcl = ((lane & (HL - 1)) == 0) ? (lane | (HL - 1)) : (lane - 1);
#pragma unroll
  for (int r = 0; r < 64; ++r) {
    float pv = shflx(v[r], HL);
    float s = v[r] + pv;
    float d = up ? (pv - v[r]) : (v[r] - pv);
    v[r] = up ? d : s;
  }
  float dw = shfls(v[63], srcl);   // neighbor diff[63] for the r==0 roll
#pragma unroll
  for (int r = 63; r >= 1; --r) {
    float d2 = v[r] + v[r - 1];
    v[r] = up ? d2 : v[r];
  }
  float d2 = v[0] + dw;
  v[0] = up ? d2 : v[0];
}

__device__ __forceinline__ void fhh_regs(float v[64], int lane) {
  stage_xlane<32>(v, lane);
  stage_xlane<16>(v, lane);
  stage_xlane<8>(v, lane);
  stage_xlane<4>(v, lane);
  stage_xlane<2>(v, lane);
  stage_xlane<1>(v, lane);
  stage_inlane<32>(v);
  stage_inlane<16>(v);
  stage_inlane<8>(v);
  stage_inlane<4>(v);
  stage_inlane<2>(v);
  stage_inlane<1>(v);
}

__global__ __launch_bounds__(TPB, 2) void aleph_fused(
    const float* __restrict__ x, const float* __restrict__ sw,
    const float* __restrict__ V, const int* __restrict__ I,
    float* __restrict__ out) {
  // interleaved bf16: (d, row) at byte swz8(d) + 2*row.  64 KB.
  __shared__ unsigned short lds[DIM * ROWS];
  char* lb = (char*)lds;
  const int t = threadIdx.x;
  const int w = t >> 6;          // wave id = row within block (0..7)
  const int lane = t & 63;
  const size_t row = (size_t)blockIdx.x * ROWS + w;

  float v[64];
  {
    const float4* xp = (const float4*)(x + row * DIM + (size_t)lane * 64);
#pragma unroll
    for (int i = 0; i < 16; ++i) {
      float4 f = xp[i];
      v[4 * i] = f.x; v[4 * i + 1] = f.y; v[4 * i + 2] = f.z; v[4 * i + 3] = f.w;
    }
  }
  fhh_regs(v, lane);   // wave chunk: lane holds d = 64*lane + r

#pragma unroll
  for (int r = 0; r < 64; ++r)
    *(unsigned short*)(lb + swz8(64 * lane + r) + 2 * w) = bfp(v[r]);
  __syncthreads();

  // Gather: thread t owns d = ii*512 + t; one ds_read_b128 yields all 8 rows.
  float preg[DPT][ROWS];
#pragma unroll
  for (int ii = 0; ii < DPT; ++ii) {
    const int d = ii * TPB + t;
    const float swd = sw[d];
    uint4 q = *(const uint4*)(lb + swz8(d));
    float a0 = blo(q.x) * swd, a1 = bhi(q.x) * swd;
    float a2 = blo(q.y) * swd, a3 = bhi(q.y) * swd;
    float a4 = blo(q.z) * swd, a5 = bhi(q.z) * swd;
    float a6 = blo(q.w) * swd, a7 = bhi(q.w) * swd;
    const int4*   ip = (const int4*)(I + d * KNZ);
    const float4* vp = (const float4*)(V + d * KNZ);
#pragma unroll 5
    for (int g = 0; g < KNZ / 4; ++g) {
      int4 i4 = ip[g];
      float4 f4 = vp[g];
      {
        uint4 qa = *(const uint4*)(lb + swz8(i4.x));
        a0 += blo(qa.x) * f4.x; a1 += bhi(qa.x) * f4.x;
        a2 += blo(qa.y) * f4.x; a3 += bhi(qa.y) * f4.x;
        a4 += blo(qa.z) * f4.x; a5 += bhi(qa.z) * f4.x;
        a6 += blo(qa.w) * f4.x; a7 += bhi(qa.w) * f4.x;
      }
      {
        uint4 qa = *(const uint4*)(lb + swz8(i4.y));
        a0 += blo(qa.x) * f4.y; a1 += bhi(qa.x) * f4.y;
        a2 += blo(qa.y) * f4.y; a3 += bhi(qa.y) * f4.y;
        a4 += blo(qa.z) * f4.y; a5 += bhi(qa.z) * f4.y;
        a6 += blo(qa.w) * f4.y; a7 += bhi(qa.w) * f4.y;
      }
      {
        uint4 qa = *(const uint4*)(lb + swz8(i4.z));
        a0 += blo(qa.x) * f4.z; a1 += bhi(qa.x) * f4.z;
        a2 += blo(qa.y) * f4.z; a3 += bhi(qa.y) * f4.z;
        a4 += blo(qa.z) * f4.z; a5 += bhi(qa.z) * f4.z;
        a6 += blo(qa.w) * f4.z; a7 += bhi(qa.w) * f4.z;
      }
      {
        uint4 qa = *(const uint4*)(lb + swz8(i4.w));
        a0 += blo(qa.x) * f4.w; a1 += bhi(qa.x) * f4.w;
        a2 += blo(qa.y) * f4.w; a3 += bhi(qa.y) * f4.w;
        a4 += blo(qa.z) * f4.w; a5 += bhi(qa.z) * f4.w;
        a6 += blo(qa.w) * f4.w; a7 += bhi(qa.w) * f4.w;
      }
    }
    preg[ii][0] = a0; preg[ii][1] = a1; preg[ii][2] = a2; preg[ii][3] = a3;
    preg[ii][4] = a4; preg[ii][5] = a5; preg[ii][6] = a6; preg[ii][7] = a7;
  }
  __syncthreads();   // all gathers done before in-place overwrite

#pragma unroll
  for (int ii = 0; ii < DPT; ++ii) {
    const int d = ii * TPB + t;
    uint4 pk;
    pk.x = (unsigned)bfp(preg[ii][0]) | ((unsigned)bfp(preg[ii][1]) << 16);
    pk.y = (unsigned)bfp(preg[ii][2]) | ((unsigned)bfp(preg[ii][3]) << 16);
    pk.z = (unsigned)bfp(preg[ii][4]) | ((unsigned)bfp(preg[ii][5]) << 16);
    pk.w = (unsigned)bfp(preg[ii][6]) | ((unsigned)bfp(preg[ii][7]) << 16);
    *(uint4*)(lb + swz8(d)) = pk;
  }
  __syncthreads();

#pragma unroll
  for (int r = 0; r < 64; ++r)
    v[r] = bfu(*(const unsigned short*)(lb + swz8(64 * lane + r) + 2 * w));
  fhh_regs(v, lane);

  const float inv = 1.0f / (float)DIM;
  float4* op = (float4*)(out + row * DIM + (size_t)lane * 64);
#pragma unroll
  for (int i = 0; i < 16; ++i) {
    float4 f;
    f.x = v[4 * i] * inv;     f.y = v[4 * i + 1] * inv;
    f.z = v[4 * i + 2] * inv; f.w = v[4 * i + 3] * inv;
    op[i] = f;
  }
}

extern "C" void kernel_launch(void* const* d_in, const int* in_sizes, int n_in,
                              void* d_out, int out_size, void* d_ws, size_t ws_size,
                              hipStream_t stream) {
  const float* x  = (const float*)d_in[0];   // (2048, 4096) f32
  const float* sw = (const float*)d_in[1];   // (4096,) f32
  const float* V  = (const float*)d_in[2];   // (4096, 40) f32
  const int*   I  = (const int*)d_in[3];     // (4096, 40) i32
  float* out = (float*)d_out;                // (2048, 4096) f32

  dim3 grid(BATCH / ROWS), block(TPB);
  hipLaunchKernelGGL(aleph_fused, grid, block, 0, stream, x, sw, V, I, out);
}

// Round 5
// 78.009 us; speedup vs baseline: 2.4563x; 1.0762x over previous
//
#include <hip/hip_runtime.h>

#define DIM   4096
#define BATCH 2048
#define KNZ   40
#define ROWS  8
#define TPB   512
#define DPT   (DIM / TPB)   // 8 d's per thread

typedef int i32x2 __attribute__((ext_vector_type(2)));

__device__ __forceinline__ float shflx(float v, int m) { return __shfl_xor(v, m, 64); }
__device__ __forceinline__ float shfls(float v, int s) { return __shfl(v, s, 64); }

// byte offset of the 16B row-group for dim index d (8 bf16 rows interleaved).
__device__ __forceinline__ int swz8(int d) { return (d << 4) ^ ((d >> 2) & 0x1f0); }

__device__ __forceinline__ unsigned short bfp(float f) {   // f32 -> bf16 RNE
  unsigned u = __float_as_uint(f);
  u += 0x7fffu + ((u >> 16) & 1u);
  return (unsigned short)(u >> 16);
}
__device__ __forceinline__ float bfu(unsigned short h) { return __uint_as_float(((unsigned)h) << 16); }
__device__ __forceinline__ float blo(unsigned u) { return __uint_as_float(u << 16); }
__device__ __forceinline__ float bhi(unsigned u) { return __uint_as_float(u & 0xffff0000u); }

template<int CTRL>
__device__ __forceinline__ float dppf(float x) {
  int i = __float_as_int(x);
  return __int_as_float(__builtin_amdgcn_update_dpp(i, i, CTRL, 0xF, 0xF, false));
}

// One butterfly element: lower lane -> sum, upper lane -> (left - right).
// Convention-proof forms: permlane*_swap(self,self) returns {self,partner} in
// SOME order, so s = rr.x+rr.y is order-independent and up-diff = s - 2*self.
template<int HL>
__device__ __forceinline__ float bfly1(float self, bool up) {
#if __has_builtin(__builtin_amdgcn_permlane32_swap)
  if constexpr (HL == 32) {
    i32x2 rr = __builtin_amdgcn_permlane32_swap(__float_as_int(self), __float_as_int(self), false, false);
    float s = __int_as_float(rr.x) + __int_as_float(rr.y);
    return up ? (s - 2.0f * self) : s;
  }
#endif
#if __has_builtin(__builtin_amdgcn_permlane16_swap)
  if constexpr (HL == 16) {
    i32x2 rr = __builtin_amdgcn_permlane16_swap(__float_as_int(self), __float_as_int(self), false, false);
    float s = __int_as_float(rr.x) + __int_as_float(rr.y);
    return up ? (s - 2.0f * self) : s;
  }
#endif
  float pv;
  if constexpr (HL == 8)      pv = dppf<0x128>(self);  // row_ror:8 == lane^8 (self-inverse)
  else if constexpr (HL == 2) pv = dppf<0x4E>(self);   // quad_perm [2,3,0,1] == lane^2
  else if constexpr (HL == 1) pv = dppf<0xB1>(self);   // quad_perm [1,0,3,2] == lane^1
  else                        pv = shflx(self, HL);    // HL==4 (+ permlane fallbacks)
  float s = self + pv;
  float d = up ? (pv - self) : (self - pv);            // exact partner: left - right
  return up ? d : s;
}

// In-lane stage for h <= 32: blocks of 2H inside the lane's 64-elem chunk.
template<int H>
__device__ __forceinline__ void stage_inlane(float v[64]) {
#pragma unroll
  for (int o = 0; o < 64; o += 2 * H) {
    float dt[H];
#pragma unroll
    for (int i = 0; i < H; ++i) {
      float a = v[o + i], b = v[o + H + i];
      dt[i] = a - b;
      v[o + i] = a + b;
    }
#pragma unroll
    for (int i = H - 1; i >= 1; --i) v[o + H + i] = dt[i] + dt[i - 1];
    v[o + H] = dt[0] + dt[H - 1];
  }
}

// Cross-lane stage for h >= 64 (HL = h/64): butterfly + roll of diff branch.
template<int HL>
__device__ __forceinline__ void stage_xlane(float v[64], int lane) {
  const bool up = (lane & HL) != 0;
  const int srcl = ((lane & (HL - 1)) == 0) ? (lane | (HL - 1)) : (lane - 1);
#pragma unroll
  for (int r = 0; r < 64; ++r) v[r] = bfly1<HL>(v[r], up);
  float dw = shfls(v[63], srcl);   // neighbor diff[63] for the r==0 roll
#pragma unroll
  for (int r = 63; r >= 1; --r) {
    float d2 = v[r] + v[r - 1];
    v[r] = up ? d2 : v[r];
  }
  float d2 = v[0] + dw;
  v[0] = up ? d2 : v[0];
}

__device__ __forceinline__ void fhh_regs(float v[64], int lane) {
  stage_xlane<32>(v, lane);
  stage_xlane<16>(v, lane);
  stage_xlane<8>(v, lane);
  stage_xlane<4>(v, lane);
  stage_xlane<2>(v, lane);
  stage_xlane<1>(v, lane);
  stage_inlane<32>(v);
  stage_inlane<16>(v);
  stage_inlane<8>(v);
  stage_inlane<4>(v);
  stage_inlane<2>(v);
  stage_inlane<1>(v);
}

__global__ __launch_bounds__(TPB, 2) void aleph_fused(
    const float* __restrict__ x, const float* __restrict__ sw,
    const float* __restrict__ V, const int* __restrict__ I,
    float* __restrict__ out) {
  // interleaved bf16: (d, row) at byte swz8(d) + 2*row.  64 KB.
  __shared__ unsigned short lds[DIM * ROWS];
  char* lb = (char*)lds;
  const int t = threadIdx.x;
  const int w = t >> 6;          // wave id = row within block (0..7)
  const int lane = t & 63;
  const size_t row = (size_t)blockIdx.x * ROWS + w;

  float v[64];
  {
    const float4* xp = (const float4*)(x + row * DIM + (size_t)lane * 64);
#pragma unroll
    for (int i = 0; i < 16; ++i) {
      float4 f = xp[i];
      v[4 * i] = f.x; v[4 * i + 1] = f.y; v[4 * i + 2] = f.z; v[4 * i + 3] = f.w;
    }
  }
  fhh_regs(v, lane);   // wave chunk: lane holds d = 64*lane + r

#pragma unroll
  for (int r = 0; r < 64; ++r)
    *(unsigned short*)(lb + swz8(64 * lane + r) + 2 * w) = bfp(v[r]);
  __syncthreads();

  // Gather: thread t owns d = ii*512 + t; one ds_read_b128 yields all 8 rows.
  float preg[DPT][ROWS];
#pragma unroll
  for (int ii = 0; ii < DPT; ++ii) {
    const int d = ii * TPB + t;
    const float swd = sw[d];
    uint4 q = *(const uint4*)(lb + swz8(d));
    float a0 = blo(q.x) * swd, a1 = bhi(q.x) * swd;
    float a2 = blo(q.y) * swd, a3 = bhi(q.y) * swd;
    float a4 = blo(q.z) * swd, a5 = bhi(q.z) * swd;
    float a6 = blo(q.w) * swd, a7 = bhi(q.w) * swd;
    const int4*   ip = (const int4*)(I + d * KNZ);
    const float4* vp = (const float4*)(V + d * KNZ);
#pragma unroll 5
    for (int g = 0; g < KNZ / 4; ++g) {
      int4 i4 = ip[g];
      float4 f4 = vp[g];
      {
        uint4 qa = *(const uint4*)(lb + swz8(i4.x));
        a0 += blo(qa.x) * f4.x; a1 += bhi(qa.x) * f4.x;
        a2 += blo(qa.y) * f4.x; a3 += bhi(qa.y) * f4.x;
        a4 += blo(qa.z) * f4.x; a5 += bhi(qa.z) * f4.x;
        a6 += blo(qa.w) * f4.x; a7 += bhi(qa.w) * f4.x;
      }
      {
        uint4 qa = *(const uint4*)(lb + swz8(i4.y));
        a0 += blo(qa.x) * f4.y; a1 += bhi(qa.x) * f4.y;
        a2 += blo(qa.y) * f4.y; a3 += bhi(qa.y) * f4.y;
        a4 += blo(qa.z) * f4.y; a5 += bhi(qa.z) * f4.y;
        a6 += blo(qa.w) * f4.y; a7 += bhi(qa.w) * f4.y;
      }
      {
        uint4 qa = *(const uint4*)(lb + swz8(i4.z));
        a0 += blo(qa.x) * f4.z; a1 += bhi(qa.x) * f4.z;
        a2 += blo(qa.y) * f4.z; a3 += bhi(qa.y) * f4.z;
        a4 += blo(qa.z) * f4.z; a5 += bhi(qa.z) * f4.z;
        a6 += blo(qa.w) * f4.z; a7 += bhi(qa.w) * f4.z;
      }
      {
        uint4 qa = *(const uint4*)(lb + swz8(i4.w));
        a0 += blo(qa.x) * f4.w; a1 += bhi(qa.x) * f4.w;
        a2 += blo(qa.y) * f4.w; a3 += bhi(qa.y) * f4.w;
        a4 += blo(qa.z) * f4.w; a5 += bhi(qa.z) * f4.w;
        a6 += blo(qa.w) * f4.w; a7 += bhi(qa.w) * f4.w;
      }
    }
    preg[ii][0] = a0; preg[ii][1] = a1; preg[ii][2] = a2; preg[ii][3] = a3;
    preg[ii][4] = a4; preg[ii][5] = a5; preg[ii][6] = a6; preg[ii][7] = a7;
  }
  __syncthreads();   // all gathers done before in-place overwrite

#pragma unroll
  for (int ii = 0; ii < DPT; ++ii) {
    const int d = ii * TPB + t;
    uint4 pk;
    pk.x = (unsigned)bfp(preg[ii][0]) | ((unsigned)bfp(preg[ii][1]) << 16);
    pk.y = (unsigned)bfp(preg[ii][2]) | ((unsigned)bfp(preg[ii][3]) << 16);
    pk.z = (unsigned)bfp(preg[ii][4]) | ((unsigned)bfp(preg[ii][5]) << 16);
    pk.w = (unsigned)bfp(preg[ii][6]) | ((unsigned)bfp(preg[ii][7]) << 16);
    *(uint4*)(lb + swz8(d)) = pk;
  }
  __syncthreads();

#pragma unroll
  for (int r = 0; r < 64; ++r)
    v[r] = bfu(*(const unsigned short*)(lb + swz8(64 * lane + r) + 2 * w));
  fhh_regs(v, lane);

  const float inv = 1.0f / (float)DIM;
  float4* op = (float4*)(out + row * DIM + (size_t)lane * 64);
#pragma unroll
  for (int i = 0; i < 16; ++i) {
    float4 f;
    f.x = v[4 * i] * inv;     f.y = v[4 * i + 1] * inv;
    f.z = v[4 * i + 2] * inv; f.w = v[4 * i + 3] * inv;
    op[i] = f;
  }
}

extern "C" void kernel_launch(void* const* d_in, const int* in_sizes, int n_in,
                              void* d_out, int out_size, void* d_ws, size_t ws_size,
                              hipStream_t stream) {
  const float* x  = (const float*)d_in[0];   // (2048, 4096) f32
  const float* sw = (const float*)d_in[1];   // (4096,) f32
  const float* V  = (const float*)d_in[2];   // (4096, 40) f32
  const int*   I  = (const int*)d_in[3];     // (4096, 40) i32
  float* out = (float*)d_out;                // (2048, 4096) f32

  dim3 grid(BATCH / ROWS), block(TPB);
  hipLaunchKernelGGL(aleph_fused, grid, block, 0, stream, x, sw, V, I, out);
}